// Round 8
// baseline (376.319 us; speedup 1.0000x reference)
//
#include <hip/hip_runtime.h>
#include <hip/hip_bf16.h>
#include <math.h>

#define EMB   128
#define ATTR  16
#define KDIM  272
#define KPAD  288            // K padded to 9 * 32
#define HID   64

typedef short s16x8 __attribute__((ext_vector_type(8)));
typedef float f32x4 __attribute__((ext_vector_type(4)));

union FragB { ushort s[8]; uint4 q; s16x8 v; };
union FragA { __hip_bfloat162 h2[4]; s16x8 v; };

static __device__ __forceinline__ ushort f2bf(float f) {
    union { float f; uint u; } v; v.f = f;
    uint u = v.u;
    return (ushort)((u + 0x7FFFu + ((u >> 16) & 1u)) >> 16);  // RNE
}

// ---- prep: w1t[j][k] = bf16(W1[k][j]), K zero-padded to 288 ----
__global__ void prep_w1t(const float* __restrict__ W1, ushort* __restrict__ w1t) {
    int idx = blockIdx.x * blockDim.x + threadIdx.x;   // 0 .. 64*288-1
    int j = idx / KPAD;
    int k = idx - j * KPAD;
    float v = (k < KDIM) ? W1[k * HID + j] : 0.f;
    w1t[idx] = f2bf(v);
}

// No LDS, no barrier: each wave independently computes 16 edges x 64 hidden.
// A-fragments load straight from global: lane (rl,kh) reads 32 contiguous bytes
// of its edge's z-row per k-step; the 4 kh-groups tile the row exactly once.
__global__ __launch_bounds__(256, 6)
void edge_mlp_direct(const float* __restrict__ z,
                     const int*   __restrict__ eidx,   // [2][E]
                     const float* __restrict__ attr,   // [E][16]
                     const ushort* __restrict__ w1t,   // [64][288] bf16
                     const float* __restrict__ b1,     // [64]
                     const float* __restrict__ w2,     // [64]
                     const float* __restrict__ b2,     // [1]
                     float*       __restrict__ out,    // [E]
                     int E, int n_nodes)
{
    const int tid  = threadIdx.x;
    const int lane = tid & 63;
    const int wv   = tid >> 6;
    const int rl   = lane & 15;      // A row (edge within wave tile) / B,D col
    const int kh   = lane >> 4;      // k-quarter selector (0..3)

    const int ebase = (blockIdx.x * 4 + wv) * 16;
    int eg = ebase + rl;
    const bool valid = (eg < E);
    if (!valid) eg = E - 1;          // safe address formation; stores guarded

    int si = eidx[eg];      if ((unsigned)si >= (unsigned)n_nodes) si = 0;
    int di = eidx[E + eg];  if ((unsigned)di >= (unsigned)n_nodes) di = 0;

    const float4* __restrict__ sp = reinterpret_cast<const float4*>(z + (size_t)si * EMB);
    const float4* __restrict__ dp = reinterpret_cast<const float4*>(z + (size_t)di * EMB);
    const float4* __restrict__ ap = reinterpret_cast<const float4*>(attr + (size_t)eg * ATTR);
    const ushort* __restrict__ wp = w1t + (size_t)rl * KPAD + kh * 8;

    f32x4 acc[4];
    #pragma unroll
    for (int nf = 0; nf < 4; ++nf) acc[nf] = (f32x4){0.f, 0.f, 0.f, 0.f};

    #pragma unroll
    for (int s = 0; s < 9; ++s) {
        // ---- A-fragment: 8 fp32 -> 8 bf16 (k = s*32 + kh*8 .. +8)
        float4 f0, f1;
        if (s < 4) {                      // src row, k in [0,128)
            f0 = sp[s * 8 + kh * 2];
            f1 = sp[s * 8 + kh * 2 + 1];
        } else if (s < 8) {               // dst row, k in [128,256)
            f0 = dp[(s - 4) * 8 + kh * 2];
            f1 = dp[(s - 4) * 8 + kh * 2 + 1];
        } else if (kh < 2) {              // attr, k in [256,272)
            f0 = ap[kh * 2];
            f1 = ap[kh * 2 + 1];
        } else {                          // zero pad, k in [272,288)
            f0 = make_float4(0.f, 0.f, 0.f, 0.f);
            f1 = f0;
        }
        FragA a;
        a.h2[0] = __float22bfloat162_rn(make_float2(f0.x, f0.y));
        a.h2[1] = __float22bfloat162_rn(make_float2(f0.z, f0.w));
        a.h2[2] = __float22bfloat162_rn(make_float2(f1.x, f1.y));
        a.h2[3] = __float22bfloat162_rn(make_float2(f1.z, f1.w));

        // ---- B-fragments + MFMA (B L1-resident: w1t is 36 KB, read by all waves)
        #pragma unroll
        for (int nf = 0; nf < 4; ++nf) {
            FragB b;
            b.q = *reinterpret_cast<const uint4*>(wp + (size_t)nf * 16 * KPAD + s * 32);
            acc[nf] = __builtin_amdgcn_mfma_f32_16x16x32_bf16(a.v, b.v, acc[nf], 0, 0, 0);
        }
    }

    // ---- epilogue: bias + relu + W2 dot (fp32), reduce over 16 cols, sigmoid
    float p[4] = {0.f, 0.f, 0.f, 0.f};
    #pragma unroll
    for (int nf = 0; nf < 4; ++nf) {
        const int j = nf * 16 + rl;
        const float bb = b1[j];
        const float ww = w2[j];
        #pragma unroll
        for (int r = 0; r < 4; ++r) {
            float h = acc[nf][r] + bb;    // D row = 4*kh + r  (edge), col = j
            h = fmaxf(h, 0.f);
            p[r] = fmaf(h, ww, p[r]);
        }
    }
    #pragma unroll
    for (int m = 1; m <= 8; m <<= 1) {    // reduce across rl lanes (hidden dim)
        #pragma unroll
        for (int r = 0; r < 4; ++r) p[r] += __shfl_xor(p[r], m, 64);
    }
    if (rl == 0) {
        const float bb2 = b2[0];
        const int eout = ebase + kh * 4;  // D row = 4*kh + r
        #pragma unroll
        for (int r = 0; r < 4; ++r) {
            if (eout + r < E) {
                const float sv = p[r] + bb2;
                out[eout + r] = 1.f / (1.f + expf(-sv));
            }
        }
    }
}

extern "C" void kernel_launch(void* const* d_in, const int* in_sizes, int n_in,
                              void* d_out, int out_size, void* d_ws, size_t ws_size,
                              hipStream_t stream)
{
    const float* z  = (const float*)d_in[0];
    const int*   ei = (const int*)  d_in[1];
    const float* ea = (const float*)d_in[2];
    const float* W1 = (const float*)d_in[3];
    const float* b1 = (const float*)d_in[4];
    const float* W2 = (const float*)d_in[5];
    const float* b2 = (const float*)d_in[6];
    float* out = (float*)d_out;

    const int E       = in_sizes[1] / 2;     // edge_index is [2][E]
    const int n_nodes = in_sizes[0] / EMB;

    ushort* w1t = (ushort*)d_ws;             // 64*288*2 = 36,864 B

    hipLaunchKernelGGL(prep_w1t, dim3((HID * KPAD) / 256), dim3(256), 0, stream, W1, w1t);

    const int grid = (E + 63) / 64;          // 64 edges per block (4 waves x 16)
    hipLaunchKernelGGL(edge_mlp_direct, dim3(grid), dim3(256), 0, stream,
                       z, ei, ea, w1t, b1, W2, b2, out, E, n_nodes);
}

// Round 9
// 268.695 us; speedup vs baseline: 1.4005x; 1.4005x over previous
//
#include <hip/hip_runtime.h>
#include <hip/hip_bf16.h>
#include <math.h>

#define EMB   128
#define ATTR  16
#define KDIM  272
#define KPAD  288            // K padded to 9 * 32
#define HID   64

typedef short s16x8 __attribute__((ext_vector_type(8)));
typedef float f32x4 __attribute__((ext_vector_type(4)));

union FragB { ushort s[8]; uint4 q; s16x8 v; };
union FragA { __hip_bfloat162 h2[4]; s16x8 v; };

static __device__ __forceinline__ ushort f2bf(float f) {
    union { float f; uint u; } v; v.f = f;
    uint u = v.u;
    return (ushort)((u + 0x7FFFu + ((u >> 16) & 1u)) >> 16);  // RNE
}

// ---- prep: w1t[j][k] = bf16(W1[k][j]), K zero-padded to 288 ----
__global__ void prep_w1t(const float* __restrict__ W1, ushort* __restrict__ w1t) {
    int idx = blockIdx.x * blockDim.x + threadIdx.x;   // 0 .. 64*288-1
    int j = idx / KPAD;
    int k = idx - j * KPAD;
    float v = (k < KDIM) ? W1[k * HID + j] : 0.f;
    w1t[idx] = f2bf(v);
}

// B (w1t) staged in LDS once per block; A gathered direct from global.
// Each wave: 32 edges (2 row-blocks) x 64 hidden; B-frags shared across both.
__global__ __launch_bounds__(256, 4)
void edge_mlp_blds(const float* __restrict__ z,
                   const int*   __restrict__ eidx,   // [2][E]
                   const float* __restrict__ attr,   // [E][16]
                   const ushort* __restrict__ w1t,   // [64][288] bf16
                   const float* __restrict__ b1,     // [64]
                   const float* __restrict__ w2,     // [64]
                   const float* __restrict__ b2,     // [1]
                   float*       __restrict__ out,    // [E]
                   int E, int n_nodes)
{
    __shared__ ushort blds[HID * KPAD];   // 36,864 B

    const int tid = threadIdx.x;

    // ---- stage B into LDS: 2304 uint4, 9 per thread, coalesced both sides.
    // 16B-unit index u: row j = u/36, slot c = u%36 -> bank groups cycle uniformly.
    {
        const uint4* __restrict__ src = reinterpret_cast<const uint4*>(w1t);
        uint4* dst = reinterpret_cast<uint4*>(blds);
        #pragma unroll
        for (int i = 0; i < 9; ++i) dst[tid + i * 256] = src[tid + i * 256];
    }
    __syncthreads();

    const int lane = tid & 63;
    const int wv   = tid >> 6;
    const int rl   = lane & 15;      // A row (edge within row-block) / B,D col
    const int kh   = lane >> 4;      // k-quarter selector (0..3)

    const int ebase = (blockIdx.x * 4 + wv) * 32;   // 32 edges per wave
    int eg0 = ebase + rl;        if (eg0 >= E) eg0 = E - 1;
    int eg1 = ebase + 16 + rl;   if (eg1 >= E) eg1 = E - 1;

    int si0 = eidx[eg0];      if ((unsigned)si0 >= (unsigned)n_nodes) si0 = 0;
    int di0 = eidx[E + eg0];  if ((unsigned)di0 >= (unsigned)n_nodes) di0 = 0;
    int si1 = eidx[eg1];      if ((unsigned)si1 >= (unsigned)n_nodes) si1 = 0;
    int di1 = eidx[E + eg1];  if ((unsigned)di1 >= (unsigned)n_nodes) di1 = 0;

    const float4* __restrict__ sp0 = reinterpret_cast<const float4*>(z + (size_t)si0 * EMB);
    const float4* __restrict__ dp0 = reinterpret_cast<const float4*>(z + (size_t)di0 * EMB);
    const float4* __restrict__ ap0 = reinterpret_cast<const float4*>(attr + (size_t)eg0 * ATTR);
    const float4* __restrict__ sp1 = reinterpret_cast<const float4*>(z + (size_t)si1 * EMB);
    const float4* __restrict__ dp1 = reinterpret_cast<const float4*>(z + (size_t)di1 * EMB);
    const float4* __restrict__ ap1 = reinterpret_cast<const float4*>(attr + (size_t)eg1 * ATTR);
    const ushort* __restrict__ bp  = blds + rl * KPAD + kh * 8;

    f32x4 acc[2][4];
    #pragma unroll
    for (int rb = 0; rb < 2; ++rb)
        #pragma unroll
        for (int nf = 0; nf < 4; ++nf) acc[rb][nf] = (f32x4){0.f, 0.f, 0.f, 0.f};

    #pragma unroll
    for (int s = 0; s < 9; ++s) {
        // ---- A-fragments for both row-blocks: 8 fp32 -> 8 bf16 each
        float4 f00, f01, f10, f11;
        if (s < 4) {
            f00 = sp0[s * 8 + kh * 2]; f01 = sp0[s * 8 + kh * 2 + 1];
            f10 = sp1[s * 8 + kh * 2]; f11 = sp1[s * 8 + kh * 2 + 1];
        } else if (s < 8) {
            f00 = dp0[(s - 4) * 8 + kh * 2]; f01 = dp0[(s - 4) * 8 + kh * 2 + 1];
            f10 = dp1[(s - 4) * 8 + kh * 2]; f11 = dp1[(s - 4) * 8 + kh * 2 + 1];
        } else if (kh < 2) {
            f00 = ap0[kh * 2]; f01 = ap0[kh * 2 + 1];
            f10 = ap1[kh * 2]; f11 = ap1[kh * 2 + 1];
        } else {
            f00 = make_float4(0.f, 0.f, 0.f, 0.f); f01 = f00; f10 = f00; f11 = f00;
        }
        FragA a0, a1;
        a0.h2[0] = __float22bfloat162_rn(make_float2(f00.x, f00.y));
        a0.h2[1] = __float22bfloat162_rn(make_float2(f00.z, f00.w));
        a0.h2[2] = __float22bfloat162_rn(make_float2(f01.x, f01.y));
        a0.h2[3] = __float22bfloat162_rn(make_float2(f01.z, f01.w));
        a1.h2[0] = __float22bfloat162_rn(make_float2(f10.x, f10.y));
        a1.h2[1] = __float22bfloat162_rn(make_float2(f10.z, f10.w));
        a1.h2[2] = __float22bfloat162_rn(make_float2(f11.x, f11.y));
        a1.h2[3] = __float22bfloat162_rn(make_float2(f11.z, f11.w));

        // ---- B from LDS, shared by both row-blocks
        #pragma unroll
        for (int nf = 0; nf < 4; ++nf) {
            FragB b;
            b.q = *reinterpret_cast<const uint4*>(bp + nf * 16 * KPAD + s * 32);
            acc[0][nf] = __builtin_amdgcn_mfma_f32_16x16x32_bf16(a0.v, b.v, acc[0][nf], 0, 0, 0);
            acc[1][nf] = __builtin_amdgcn_mfma_f32_16x16x32_bf16(a1.v, b.v, acc[1][nf], 0, 0, 0);
        }
    }

    // ---- epilogue per row-block: bias + relu + W2 dot, reduce over rl, sigmoid
    const float bb2 = b2[0];
    #pragma unroll
    for (int rb = 0; rb < 2; ++rb) {
        float p[4] = {0.f, 0.f, 0.f, 0.f};
        #pragma unroll
        for (int nf = 0; nf < 4; ++nf) {
            const int j = nf * 16 + rl;
            const float bb = b1[j];
            const float ww = w2[j];
            #pragma unroll
            for (int r = 0; r < 4; ++r) {
                float h = acc[rb][nf][r] + bb;   // D row = 4*kh + r (edge), col = j
                h = fmaxf(h, 0.f);
                p[r] = fmaf(h, ww, p[r]);
            }
        }
        #pragma unroll
        for (int m = 1; m <= 8; m <<= 1) {       // reduce across rl lanes (hidden)
            #pragma unroll
            for (int r = 0; r < 4; ++r) p[r] += __shfl_xor(p[r], m, 64);
        }
        if (rl == 0) {
            const int eout = ebase + rb * 16 + kh * 4;   // D row = 4*kh + r
            #pragma unroll
            for (int r = 0; r < 4; ++r) {
                if (eout + r < E) {
                    const float sv = p[r] + bb2;
                    out[eout + r] = 1.f / (1.f + expf(-sv));
                }
            }
        }
    }
}

extern "C" void kernel_launch(void* const* d_in, const int* in_sizes, int n_in,
                              void* d_out, int out_size, void* d_ws, size_t ws_size,
                              hipStream_t stream)
{
    const float* z  = (const float*)d_in[0];
    const int*   ei = (const int*)  d_in[1];
    const float* ea = (const float*)d_in[2];
    const float* W1 = (const float*)d_in[3];
    const float* b1 = (const float*)d_in[4];
    const float* W2 = (const float*)d_in[5];
    const float* b2 = (const float*)d_in[6];
    float* out = (float*)d_out;

    const int E       = in_sizes[1] / 2;     // edge_index is [2][E]
    const int n_nodes = in_sizes[0] / EMB;

    ushort* w1t = (ushort*)d_ws;             // 64*288*2 = 36,864 B

    hipLaunchKernelGGL(prep_w1t, dim3((HID * KPAD) / 256), dim3(256), 0, stream, W1, w1t);

    const int grid = (E + 127) / 128;        // 128 edges per block (4 waves x 32)
    hipLaunchKernelGGL(edge_mlp_blds, dim3(grid), dim3(256), 0, stream,
                       z, ei, ea, w1t, b1, W2, b2, out, E, n_nodes);
}

// Round 13
// 221.343 us; speedup vs baseline: 1.7002x; 1.2139x over previous
//
#include <hip/hip_runtime.h>
#include <hip/hip_bf16.h>
#include <math.h>

#define EMB   128
#define ATTR  16
#define KDIM  272
#define KPAD  288            // K padded to 9 * 32
#define HID   64

typedef short s16x8 __attribute__((ext_vector_type(8)));
typedef float f32x4 __attribute__((ext_vector_type(4)));

union FragB { ushort s[8]; uint4 q; s16x8 v; };
union FragA { __hip_bfloat162 h2[4]; uint4 q; s16x8 v; };

static __device__ __forceinline__ ushort f2bf(float f) {
    union { float f; uint u; } v; v.f = f;
    uint u = v.u;
    return (ushort)((u + 0x7FFFu + ((u >> 16) & 1u)) >> 16);  // RNE
}

// ---- merged prep: blocks [0,nzb) convert z fp32->bf16 (coalesced);
//      blocks [nzb,nzb+72) build w1t[j][k] = bf16(W1[k][j]) zero-padded.
__global__ void prep_all(const float* __restrict__ z, ushort* __restrict__ zb,
                         const float* __restrict__ W1, ushort* __restrict__ w1t,
                         int nzb, int n_z)      // n_z = n_nodes*EMB
{
    const int bid = blockIdx.x;
    if (bid < nzb) {
        const int i = bid * 256 + threadIdx.x;     // 8 floats per thread
        const int e0 = i * 8;
        if (e0 + 8 <= n_z) {
            const float4* src = reinterpret_cast<const float4*>(z + e0);
            float4 f0 = src[0], f1 = src[1];
            FragA pk;
            pk.h2[0] = __float22bfloat162_rn(make_float2(f0.x, f0.y));
            pk.h2[1] = __float22bfloat162_rn(make_float2(f0.z, f0.w));
            pk.h2[2] = __float22bfloat162_rn(make_float2(f1.x, f1.y));
            pk.h2[3] = __float22bfloat162_rn(make_float2(f1.z, f1.w));
            *reinterpret_cast<uint4*>(zb + e0) = pk.q;
        }
    } else {
        const int idx = (bid - nzb) * 256 + threadIdx.x;   // 0 .. 64*288-1
        const int j = idx / KPAD;
        const int k = idx - j * KPAD;
        if (j < HID) {
            float v = (k < KDIM) ? W1[k * HID + j] : 0.f;
            w1t[idx] = f2bf(v);
        }
    }
}

// ---- main: B (w1t) in LDS once per block; A gathered as bf16 direct from zb.
// Each wave: 32 edges (2 row-blocks) x 64 hidden. Lane A-frag = one dwordx4.
__global__ __launch_bounds__(256, 4)
void edge_mlp_zb(const ushort* __restrict__ zb,    // [n_nodes][128] bf16
                 const int*   __restrict__ eidx,   // [2][E]
                 const float* __restrict__ attr,   // [E][16]
                 const ushort* __restrict__ w1t,   // [64][288] bf16
                 const float* __restrict__ b1,     // [64]
                 const float* __restrict__ w2,     // [64]
                 const float* __restrict__ b2,     // [1]
                 float*       __restrict__ out,    // [E]
                 int E, int n_nodes)
{
    __shared__ ushort blds[HID * KPAD];   // 36,864 B

    const int tid = threadIdx.x;
    {
        const uint4* __restrict__ src = reinterpret_cast<const uint4*>(w1t);
        uint4* dst = reinterpret_cast<uint4*>(blds);
        #pragma unroll
        for (int i = 0; i < 9; ++i) dst[tid + i * 256] = src[tid + i * 256];
    }
    __syncthreads();

    const int lane = tid & 63;
    const int wv   = tid >> 6;
    const int rl   = lane & 15;      // A row (edge within row-block) / B,D col
    const int kh   = lane >> 4;      // k-quarter selector (0..3)

    const int ebase = (blockIdx.x * 4 + wv) * 32;   // 32 edges per wave
    int eg0 = ebase + rl;        if (eg0 >= E) eg0 = E - 1;
    int eg1 = ebase + 16 + rl;   if (eg1 >= E) eg1 = E - 1;

    int si0 = eidx[eg0];      if ((unsigned)si0 >= (unsigned)n_nodes) si0 = 0;
    int di0 = eidx[E + eg0];  if ((unsigned)di0 >= (unsigned)n_nodes) di0 = 0;
    int si1 = eidx[eg1];      if ((unsigned)si1 >= (unsigned)n_nodes) si1 = 0;
    int di1 = eidx[E + eg1];  if ((unsigned)di1 >= (unsigned)n_nodes) di1 = 0;

    const ushort* __restrict__ sp0 = zb + (size_t)si0 * EMB;
    const ushort* __restrict__ dp0 = zb + (size_t)di0 * EMB;
    const ushort* __restrict__ sp1 = zb + (size_t)si1 * EMB;
    const ushort* __restrict__ dp1 = zb + (size_t)di1 * EMB;
    const float4* __restrict__ ap0 = reinterpret_cast<const float4*>(attr + (size_t)eg0 * ATTR);
    const float4* __restrict__ ap1 = reinterpret_cast<const float4*>(attr + (size_t)eg1 * ATTR);
    const ushort* __restrict__ bp  = blds + rl * KPAD + kh * 8;

    f32x4 acc[2][4];
    #pragma unroll
    for (int rb = 0; rb < 2; ++rb)
        #pragma unroll
        for (int nf = 0; nf < 4; ++nf) acc[rb][nf] = (f32x4){0.f, 0.f, 0.f, 0.f};

    #pragma unroll
    for (int s = 0; s < 9; ++s) {
        // ---- A-fragments: one 16B bf16 load each (k = s*32 + kh*8 .. +8)
        FragA a0, a1;
        if (s < 4) {
            a0.q = *reinterpret_cast<const uint4*>(sp0 + s * 32 + kh * 8);
            a1.q = *reinterpret_cast<const uint4*>(sp1 + s * 32 + kh * 8);
        } else if (s < 8) {
            a0.q = *reinterpret_cast<const uint4*>(dp0 + (s - 4) * 32 + kh * 8);
            a1.q = *reinterpret_cast<const uint4*>(dp1 + (s - 4) * 32 + kh * 8);
        } else if (kh < 2) {
            float4 f00 = ap0[kh * 2], f01 = ap0[kh * 2 + 1];
            float4 f10 = ap1[kh * 2], f11 = ap1[kh * 2 + 1];
            a0.h2[0] = __float22bfloat162_rn(make_float2(f00.x, f00.y));
            a0.h2[1] = __float22bfloat162_rn(make_float2(f00.z, f00.w));
            a0.h2[2] = __float22bfloat162_rn(make_float2(f01.x, f01.y));
            a0.h2[3] = __float22bfloat162_rn(make_float2(f01.z, f01.w));
            a1.h2[0] = __float22bfloat162_rn(make_float2(f10.x, f10.y));
            a1.h2[1] = __float22bfloat162_rn(make_float2(f10.z, f10.w));
            a1.h2[2] = __float22bfloat162_rn(make_float2(f11.x, f11.y));
            a1.h2[3] = __float22bfloat162_rn(make_float2(f11.z, f11.w));
        } else {
            a0.q = make_uint4(0u, 0u, 0u, 0u);
            a1.q = make_uint4(0u, 0u, 0u, 0u);
        }

        // ---- B from LDS, shared by both row-blocks
        #pragma unroll
        for (int nf = 0; nf < 4; ++nf) {
            FragB b;
            b.q = *reinterpret_cast<const uint4*>(bp + nf * 16 * KPAD + s * 32);
            acc[0][nf] = __builtin_amdgcn_mfma_f32_16x16x32_bf16(a0.v, b.v, acc[0][nf], 0, 0, 0);
            acc[1][nf] = __builtin_amdgcn_mfma_f32_16x16x32_bf16(a1.v, b.v, acc[1][nf], 0, 0, 0);
        }
    }

    // ---- epilogue per row-block: bias + relu + W2 dot, reduce over rl, sigmoid
    const float bb2 = b2[0];
    #pragma unroll
    for (int rb = 0; rb < 2; ++rb) {
        float p[4] = {0.f, 0.f, 0.f, 0.f};
        #pragma unroll
        for (int nf = 0; nf < 4; ++nf) {
            const int j = nf * 16 + rl;
            const float bb = b1[j];
            const float ww = w2[j];
            #pragma unroll
            for (int r = 0; r < 4; ++r) {
                float h = acc[rb][nf][r] + bb;   // D row = 4*kh + r (edge), col = j
                h = fmaxf(h, 0.f);
                p[r] = fmaf(h, ww, p[r]);
            }
        }
        #pragma unroll
        for (int m = 1; m <= 8; m <<= 1) {       // reduce across rl lanes (hidden)
            #pragma unroll
            for (int r = 0; r < 4; ++r) p[r] += __shfl_xor(p[r], m, 64);
        }
        if (rl == 0) {
            const int eout = ebase + rb * 16 + kh * 4;   // D row = 4*kh + r
            #pragma unroll
            for (int r = 0; r < 4; ++r) {
                if (eout + r < E) {
                    const float sv = p[r] + bb2;
                    out[eout + r] = 1.f / (1.f + expf(-sv));
                }
            }
        }
    }
}

// ---- fallback (proven round-9 path) if ws can't hold the bf16 z mirror ----
__global__ __launch_bounds__(256, 4)
void edge_mlp_blds(const float* __restrict__ z,
                   const int*   __restrict__ eidx,
                   const float* __restrict__ attr,
                   const ushort* __restrict__ w1t,
                   const float* __restrict__ b1,
                   const float* __restrict__ w2,
                   const float* __restrict__ b2,
                   float*       __restrict__ out,
                   int E, int n_nodes)
{
    __shared__ ushort blds[HID * KPAD];
    const int tid = threadIdx.x;
    {
        const uint4* __restrict__ src = reinterpret_cast<const uint4*>(w1t);
        uint4* dst = reinterpret_cast<uint4*>(blds);
        #pragma unroll
        for (int i = 0; i < 9; ++i) dst[tid + i * 256] = src[tid + i * 256];
    }
    __syncthreads();

    const int lane = tid & 63;
    const int wv   = tid >> 6;
    const int rl   = lane & 15;
    const int kh   = lane >> 4;

    const int ebase = (blockIdx.x * 4 + wv) * 32;
    int eg0 = ebase + rl;        if (eg0 >= E) eg0 = E - 1;
    int eg1 = ebase + 16 + rl;   if (eg1 >= E) eg1 = E - 1;

    int si0 = eidx[eg0];      if ((unsigned)si0 >= (unsigned)n_nodes) si0 = 0;
    int di0 = eidx[E + eg0];  if ((unsigned)di0 >= (unsigned)n_nodes) di0 = 0;
    int si1 = eidx[eg1];      if ((unsigned)si1 >= (unsigned)n_nodes) si1 = 0;
    int di1 = eidx[E + eg1];  if ((unsigned)di1 >= (unsigned)n_nodes) di1 = 0;

    const float4* __restrict__ sp0 = reinterpret_cast<const float4*>(z + (size_t)si0 * EMB);
    const float4* __restrict__ dp0 = reinterpret_cast<const float4*>(z + (size_t)di0 * EMB);
    const float4* __restrict__ ap0 = reinterpret_cast<const float4*>(attr + (size_t)eg0 * ATTR);
    const float4* __restrict__ sp1 = reinterpret_cast<const float4*>(z + (size_t)si1 * EMB);
    const float4* __restrict__ dp1 = reinterpret_cast<const float4*>(z + (size_t)di1 * EMB);
    const float4* __restrict__ ap1 = reinterpret_cast<const float4*>(attr + (size_t)eg1 * ATTR);
    const ushort* __restrict__ bp  = blds + rl * KPAD + kh * 8;

    f32x4 acc[2][4];
    #pragma unroll
    for (int rb = 0; rb < 2; ++rb)
        #pragma unroll
        for (int nf = 0; nf < 4; ++nf) acc[rb][nf] = (f32x4){0.f, 0.f, 0.f, 0.f};

    #pragma unroll
    for (int s = 0; s < 9; ++s) {
        float4 f00, f01, f10, f11;
        if (s < 4) {
            f00 = sp0[s * 8 + kh * 2]; f01 = sp0[s * 8 + kh * 2 + 1];
            f10 = sp1[s * 8 + kh * 2]; f11 = sp1[s * 8 + kh * 2 + 1];
        } else if (s < 8) {
            f00 = dp0[(s - 4) * 8 + kh * 2]; f01 = dp0[(s - 4) * 8 + kh * 2 + 1];
            f10 = dp1[(s - 4) * 8 + kh * 2]; f11 = dp1[(s - 4) * 8 + kh * 2 + 1];
        } else if (kh < 2) {
            f00 = ap0[kh * 2]; f01 = ap0[kh * 2 + 1];
            f10 = ap1[kh * 2]; f11 = ap1[kh * 2 + 1];
        } else {
            f00 = make_float4(0.f, 0.f, 0.f, 0.f); f01 = f00; f10 = f00; f11 = f00;
        }
        FragA a0, a1;
        a0.h2[0] = __float22bfloat162_rn(make_float2(f00.x, f00.y));
        a0.h2[1] = __float22bfloat162_rn(make_float2(f00.z, f00.w));
        a0.h2[2] = __float22bfloat162_rn(make_float2(f01.x, f01.y));
        a0.h2[3] = __float22bfloat162_rn(make_float2(f01.z, f01.w));
        a1.h2[0] = __float22bfloat162_rn(make_float2(f10.x, f10.y));
        a1.h2[1] = __float22bfloat162_rn(make_float2(f10.z, f10.w));
        a1.h2[2] = __float22bfloat162_rn(make_float2(f11.x, f11.y));
        a1.h2[3] = __float22bfloat162_rn(make_float2(f11.z, f11.w));

        #pragma unroll
        for (int nf = 0; nf < 4; ++nf) {
            FragB b;
            b.q = *reinterpret_cast<const uint4*>(bp + nf * 16 * KPAD + s * 32);
            acc[0][nf] = __builtin_amdgcn_mfma_f32_16x16x32_bf16(a0.v, b.v, acc[0][nf], 0, 0, 0);
            acc[1][nf] = __builtin_amdgcn_mfma_f32_16x16x32_bf16(a1.v, b.v, acc[1][nf], 0, 0, 0);
        }
    }

    const float bb2 = b2[0];
    #pragma unroll
    for (int rb = 0; rb < 2; ++rb) {
        float p[4] = {0.f, 0.f, 0.f, 0.f};
        #pragma unroll
        for (int nf = 0; nf < 4; ++nf) {
            const int j = nf * 16 + rl;
            const float bb = b1[j];
            const float ww = w2[j];
            #pragma unroll
            for (int r = 0; r < 4; ++r) {
                float h = acc[rb][nf][r] + bb;
                h = fmaxf(h, 0.f);
                p[r] = fmaf(h, ww, p[r]);
            }
        }
        #pragma unroll
        for (int m = 1; m <= 8; m <<= 1) {
            #pragma unroll
            for (int r = 0; r < 4; ++r) p[r] += __shfl_xor(p[r], m, 64);
        }
        if (rl == 0) {
            const int eout = ebase + rb * 16 + kh * 4;
            #pragma unroll
            for (int r = 0; r < 4; ++r) {
                if (eout + r < E) {
                    const float sv = p[r] + bb2;
                    out[eout + r] = 1.f / (1.f + expf(-sv));
                }
            }
        }
    }
}

__global__ void prep_w1t_only(const float* __restrict__ W1, ushort* __restrict__ w1t) {
    int idx = blockIdx.x * blockDim.x + threadIdx.x;
    int j = idx / KPAD;
    int k = idx - j * KPAD;
    float v = (k < KDIM) ? W1[k * HID + j] : 0.f;
    w1t[idx] = f2bf(v);
}

extern "C" void kernel_launch(void* const* d_in, const int* in_sizes, int n_in,
                              void* d_out, int out_size, void* d_ws, size_t ws_size,
                              hipStream_t stream)
{
    const float* z  = (const float*)d_in[0];
    const int*   ei = (const int*)  d_in[1];
    const float* ea = (const float*)d_in[2];
    const float* W1 = (const float*)d_in[3];
    const float* b1 = (const float*)d_in[4];
    const float* W2 = (const float*)d_in[5];
    const float* b2 = (const float*)d_in[6];
    float* out = (float*)d_out;

    const int E       = in_sizes[1] / 2;     // edge_index is [2][E]
    const int n_nodes = in_sizes[0] / EMB;
    const int n_z     = n_nodes * EMB;

    ushort* w1t = (ushort*)d_ws;                       // 36,864 B
    ushort* zb  = (ushort*)d_ws + HID * KPAD;          // n_z bf16
    const size_t needed = (size_t)HID * KPAD * 2 + (size_t)n_z * 2;

    const int grid = (E + 127) / 128;                  // 128 edges per block

    if (ws_size >= needed) {
        const int nzb = (n_z / 8 + 255) / 256;         // z-convert blocks
        const int wblk = (HID * KPAD + 255) / 256;     // w1t blocks (72)
        hipLaunchKernelGGL(prep_all, dim3(nzb + wblk), dim3(256), 0, stream,
                           z, zb, W1, w1t, nzb, n_z);
        hipLaunchKernelGGL(edge_mlp_zb, dim3(grid), dim3(256), 0, stream,
                           zb, ei, ea, w1t, b1, W2, b2, out, E, n_nodes);
    } else {
        hipLaunchKernelGGL(prep_w1t_only, dim3((HID * KPAD) / 256), dim3(256), 0, stream,
                           W1, w1t);
        hipLaunchKernelGGL(edge_mlp_blds, dim3(grid), dim3(256), 0, stream,
                           z, ei, ea, w1t, b1, W2, b2, out, E, n_nodes);
    }
}